// Round 6
// baseline (182.971 us; speedup 1.0000x reference)
//
#include <hip/hip_runtime.h>
#include <hip/hip_bf16.h>

typedef unsigned short u16;
typedef unsigned int   u32;
typedef __attribute__((ext_vector_type(8))) short s16x8;
typedef __attribute__((ext_vector_type(4))) float f32x4;

#define BN_EPS 1e-3f
// problem dims
#define NB 16
#define NC 64
#define NH 160
#define NW 160
#define NE 4
#define NR 16
#define HP 162   // padded H
#define WPD 162  // padded W

// workspace layout (bytes)
#define OFF_XT 0UL
#define SZ_XT  (16UL*162*162*64*2)     // 53,747,712  padded NHWC bf16
#define OFF_WT (OFF_XT + SZ_XT)
#define SZ_WT  (4UL*64*9*64*2)         // 294,912  [e][ch][tap][cio][co][8ci] bf16
#define OFF_SC (OFF_WT + SZ_WT)        // bn scale [4][64] f32
#define OFF_SH (OFF_SC + 1024UL)       // bn shift [4][64] f32
#define OFF_G  (OFF_SH + 1024UL)       // g [16][64] f32
#define OFF_WE (OFF_G + 4096UL)        // wexp [16][4] f32
#define OFF_GP (OFF_WE + 256UL)        // gpart [1024][800] f32 (3.28 MB)

// conv_main LDS partition (dynamic, 80,384 B total -> 2 blocks/CU)
#define XLS_BYTES (340 * 64 * 2)       // 43,520 = [cg 8][P 340] octets
#define WLS_BYTES (2304 * 16)          // 36,864 = [t 36][co 64] octets
#define SMEM_TOTAL (XLS_BYTES + WLS_BYTES)

__device__ __forceinline__ u16 f2bf(float f) {
    u32 u = __builtin_bit_cast(u32, f);
    u += 0x7fffu + ((u >> 16) & 1u);   // round-to-nearest-even
    return (u16)(u >> 16);
}

// ---- zero the 1-pixel halo border of xt ----------------------------------
__global__ void zero_border(u16* __restrict__ xt) {
    int blk = blockIdx.x;              // 16*162
    int hp = blk % 162, b = blk / 162;
    u32* row = (u32*)xt + (((long)b * 162 + hp) * 162) * 32; // 32 u32 per pixel
    int t = threadIdx.x;
    if (hp == 0 || hp == 161) {
        for (int i = t; i < 162 * 32; i += 256) row[i] = 0u;
    } else if (t < 64) {
        int p = (t >> 5) ? 161 : 0;
        row[p * 32 + (t & 31)] = 0u;
    }
}

// ---- weights [E][Co][Ci][3][3] f32 -> [e][ch][tap][cio][co][8ci] bf16 ----
// (each (e,ch) half-ci panel = 36,864 B linear; octets land at
//  [k-octet t=tap*4+cio][co] for global_load_lds)
__global__ void prep_w(const float* __restrict__ cw, u16* __restrict__ wt,
                       const float* __restrict__ gamma, const float* __restrict__ beta,
                       const float* __restrict__ mean, const float* __restrict__ var,
                       float* __restrict__ scale, float* __restrict__ shift) {
    int idx = blockIdx.x * 256 + threadIdx.x;
    if (idx < 4 * 2 * 9 * 4 * 64 * 8) {
        int cin = idx & 7;
        int t = idx >> 3;
        int co = t & 63; t >>= 6;
        int cio = t & 3; t >>= 2;
        int tap = t % 9; t /= 9;
        int ch = t & 1;
        int e = t >> 1;
        int ci = ch * 32 + cio * 8 + cin;
        wt[idx] = f2bf(cw[(((long)(e * 64 + co)) * 64 + ci) * 9 + tap]);
    }
    if (idx < 256) {
        float sc = gamma[idx] * rsqrtf(var[idx] + BN_EPS);
        scale[idx] = sc;
        shift[idx] = beta[idx] - mean[idx] * sc;
    }
}

// ---- x NCHW f32 -> padded NHWC bf16 + router partial sums ----------------
__global__ void prep_x(const float* __restrict__ x, u16* __restrict__ xt,
                       float* __restrict__ gpart) {
    __shared__ float tile[64][33];
    int blk = blockIdx.x;              // b*800 + h*5 + wt5
    int wt5 = blk % 5;
    int tmp = blk / 5;
    int h = tmp % 160, b = tmp / 160;
    int w0 = wt5 * 32;
    int t = threadIdx.x;
    int w = t & 31, c0 = t >> 5;       // c0 in 0..7
#pragma unroll
    for (int i = 0; i < 8; ++i) {
        int c = c0 + 8 * i;
        tile[c][w] = x[(((long)b * 64 + c) * 160 + h) * 160 + w0 + w];
    }
    __syncthreads();
    if (t < 64) {                      // per-channel partial sum over 32 w
        float s = 0.f;
#pragma unroll
        for (int wi = 0; wi < 32; ++wi) s += tile[t][wi];
        gpart[((long)(b * 64 + t)) * 800 + h * 5 + wt5] = s;
    }
    // write NHWC bf16 (padded coords h+1, w+1), coalesced u32 (2 channels)
    u32* xt32 = (u32*)xt;
    long base = ((((long)b * 162 + h + 1) * 162) + (w0 + 1)) * 32; // u32 index
#pragma unroll
    for (int j = 0; j < 4; ++j) {
        int idx = t + 256 * j;         // 0..1023
        int p = idx >> 5, cp = idx & 31;
        float v0 = tile[2 * cp][p], v1 = tile[2 * cp + 1][p];
        xt32[base + p * 32 + cp] = (u32)f2bf(v0) | ((u32)f2bf(v1) << 16);
    }
}

// ---- finish global average pool ------------------------------------------
__global__ void g_reduce(const float* __restrict__ gpart, float* __restrict__ g) {
    int id = blockIdx.x;               // 1024 = b*64+c
    int t = threadIdx.x;
    float s = 0.f;
    for (int i = t; i < 800; i += 256) s += gpart[(long)id * 800 + i];
#pragma unroll
    for (int off = 32; off > 0; off >>= 1) s += __shfl_down(s, off, 64);
    __shared__ float red[4];
    if ((t & 63) == 0) red[t >> 6] = s;
    __syncthreads();
    if (t == 0) g[id] = (red[0] + red[1] + red[2] + red[3]) * (1.f / 25600.f);
}

// ---- router: fc1 -> relu -> fc2 -> softmax -------------------------------
__global__ void router(const float* __restrict__ g, const float* __restrict__ fc1w,
                       const float* __restrict__ fc2w, const float* __restrict__ fc2b,
                       float* __restrict__ wexp) {
    __shared__ float gL[16][64];
    __shared__ float h1[16][16];
    __shared__ float z[16][4];
    int t = threadIdx.x;
    for (int i = t; i < 1024; i += 256) gL[i >> 6][i & 63] = g[i];
    __syncthreads();
    {
        int b = t >> 4, r = t & 15;
        float s = 0.f;
#pragma unroll
        for (int c = 0; c < 64; ++c) s += gL[b][c] * fc1w[r * 64 + c];
        h1[b][r] = fmaxf(s, 0.f);
    }
    __syncthreads();
    if (t < 64) {
        int b = t >> 2, e = t & 3;
        float s = fc2b[e];
#pragma unroll
        for (int r = 0; r < 16; ++r) s += h1[b][r] * fc2w[e * 16 + r];
        z[b][e] = s;
    }
    __syncthreads();
    if (t < 16) {
        int b = t;
        float m = fmaxf(fmaxf(z[b][0], z[b][1]), fmaxf(z[b][2], z[b][3]));
        float e0 = __expf(z[b][0] - m), e1 = __expf(z[b][1] - m);
        float e2 = __expf(z[b][2] - m), e3 = __expf(z[b][3] - m);
        float inv = 1.f / (e0 + e1 + e2 + e3);
        wexp[b * 4 + 0] = e0 * inv; wexp[b * 4 + 1] = e1 * inv;
        wexp[b * 4 + 2] = e2 * inv; wexp[b * 4 + 3] = e3 * inv;
    }
}

// ---- main: 4-expert implicit-GEMM conv + BN + SiLU + weighted sum --------
// grid 1600 = 16 b * 20 htile * 5 wtile ; block 256 (4 waves)
// Wave tile M=64co x N=64px. x in LDS as [cg][P] (channel-octet-major):
// B-reads are consecutive octets across lanes (conflict-free, no swizzle)
// and affine in tap -> ds_read offset immediates, ZERO addr VALU in K-loop.
__global__ __launch_bounds__(256, 2) void conv_main(
    const u16* __restrict__ xt, const u16* __restrict__ wt,
    const float* __restrict__ scale, const float* __restrict__ shift,
    const float* __restrict__ wexp, float* __restrict__ out) {
    extern __shared__ char smem[];
    u16* xls = (u16*)smem;                       // [cg 8][P 340] octets
    u16* wls = (u16*)(smem + XLS_BYTES);         // [t 36][co 64] octets

    // bijective chunked XCD swizzle (1600 % 8 == 0): XCD k gets 2 batches
    const int o = blockIdx.x;
    const int blk = (o & 7) * 200 + (o >> 3);
    const int wt5 = blk % 5;
    const int tmp = blk / 5;
    const int ht = tmp % 20;
    const int b = tmp / 20;
    const int h0 = ht * 8, w0 = wt5 * 32;
    const int tid = threadIdx.x;
    const int lane = tid & 63;
    const int wv = tid >> 6;
    const int l15 = lane & 15, kl = lane >> 4;

    // stage x halo tile (rows h0..h0+9, cols w0..w0+33) into [cg][P]
    {
        const u16* xb = xt + (long)b * HP * WPD * 64;
        for (int c = tid; c < 2720; c += 256) {
            int P = c >> 3, cg = c & 7;        // cg fast -> coalesced global
            int y = P / 34, px = P - y * 34;
            const u16* src = xb + (((long)(h0 + y) * WPD) + (w0 + px)) * 64 + cg * 8;
            s16x8 v = *(const s16x8*)src;
            *(s16x8*)(&xls[(cg * 340 + P) << 3]) = v;
        }
    }

    int Pbase[4];
#pragma unroll
    for (int nf = 0; nf < 4; ++nf)
        Pbase[nf] = (2 * wv + (nf >> 1)) * 34 + (nf & 1) * 16 + l15;

    // B base addresses (u16 index): [ch][nf]; K-loop adds only immediates
    int oB[2][4];
#pragma unroll
    for (int ch = 0; ch < 2; ++ch)
#pragma unroll
        for (int nf = 0; nf < 4; ++nf)
            oB[ch][nf] = (((ch * 4 + kl) * 340) + Pbase[nf]) << 3;
    // A base (u16 index into wls): t=tap*4+kl rows of 64 co
    const int oA = (kl * 64 + l15) << 3;         // + tap*2048 + mf*128

    f32x4 oacc[4][4];
#pragma unroll
    for (int i = 0; i < 4; ++i)
#pragma unroll
        for (int j = 0; j < 4; ++j) oacc[i][j] = (f32x4)(0.f);

#pragma unroll 1
    for (int e = 0; e < 4; ++e) {
        f32x4 acc[4][4];
#pragma unroll
        for (int i = 0; i < 4; ++i)
#pragma unroll
            for (int j = 0; j < 4; ++j) acc[i][j] = (f32x4)(0.f);

#pragma unroll 1
        for (int ch = 0; ch < 2; ++ch) {
            // protect wls (and, first round, xls) from in-flight readers
            __syncthreads();
            // stage weight half-ci panel: 2304 octets, linear DMA to LDS
            {
                const u16* wsrc = wt + ((long)(e * 2 + ch)) * 2304 * 8;
#pragma unroll
                for (int r = 0; r < 9; ++r) {
                    int oo = r * 256 + tid;      // octet index
                    __builtin_amdgcn_global_load_lds(
                        (const __attribute__((address_space(1))) void*)(wsrc + oo * 8),
                        (__attribute__((address_space(3))) void*)(wls + oo * 8),
                        16, 0, 0);
                }
            }
            __syncthreads();   // compiler drains vmcnt(0) before barrier

#pragma unroll
            for (int tap = 0; tap < 9; ++tap) {
                const int dy = tap / 3, dx = tap - 3 * dy;
                const int poff8 = (dy * 34 + dx) << 3;   // immediate
                const int at = oA + tap * 2048;          // immediate add
                s16x8 af0 = *(const s16x8*)(&wls[at]);
                s16x8 af1 = *(const s16x8*)(&wls[at + 128]);
                s16x8 af2 = *(const s16x8*)(&wls[at + 256]);
                s16x8 af3 = *(const s16x8*)(&wls[at + 384]);
                s16x8 bf0 = *(const s16x8*)(&xls[oB[ch][0] + poff8]);
                s16x8 bf1 = *(const s16x8*)(&xls[oB[ch][1] + poff8]);
                s16x8 bf2 = *(const s16x8*)(&xls[oB[ch][2] + poff8]);
                s16x8 bf3 = *(const s16x8*)(&xls[oB[ch][3] + poff8]);
                acc[0][0] = __builtin_amdgcn_mfma_f32_16x16x32_bf16(af0, bf0, acc[0][0], 0, 0, 0);
                acc[1][0] = __builtin_amdgcn_mfma_f32_16x16x32_bf16(af1, bf0, acc[1][0], 0, 0, 0);
                acc[2][0] = __builtin_amdgcn_mfma_f32_16x16x32_bf16(af2, bf0, acc[2][0], 0, 0, 0);
                acc[3][0] = __builtin_amdgcn_mfma_f32_16x16x32_bf16(af3, bf0, acc[3][0], 0, 0, 0);
                acc[0][1] = __builtin_amdgcn_mfma_f32_16x16x32_bf16(af0, bf1, acc[0][1], 0, 0, 0);
                acc[1][1] = __builtin_amdgcn_mfma_f32_16x16x32_bf16(af1, bf1, acc[1][1], 0, 0, 0);
                acc[2][1] = __builtin_amdgcn_mfma_f32_16x16x32_bf16(af2, bf1, acc[2][1], 0, 0, 0);
                acc[3][1] = __builtin_amdgcn_mfma_f32_16x16x32_bf16(af3, bf1, acc[3][1], 0, 0, 0);
                acc[0][2] = __builtin_amdgcn_mfma_f32_16x16x32_bf16(af0, bf2, acc[0][2], 0, 0, 0);
                acc[1][2] = __builtin_amdgcn_mfma_f32_16x16x32_bf16(af1, bf2, acc[1][2], 0, 0, 0);
                acc[2][2] = __builtin_amdgcn_mfma_f32_16x16x32_bf16(af2, bf2, acc[2][2], 0, 0, 0);
                acc[3][2] = __builtin_amdgcn_mfma_f32_16x16x32_bf16(af3, bf2, acc[3][2], 0, 0, 0);
                acc[0][3] = __builtin_amdgcn_mfma_f32_16x16x32_bf16(af0, bf3, acc[0][3], 0, 0, 0);
                acc[1][3] = __builtin_amdgcn_mfma_f32_16x16x32_bf16(af1, bf3, acc[1][3], 0, 0, 0);
                acc[2][3] = __builtin_amdgcn_mfma_f32_16x16x32_bf16(af2, bf3, acc[2][3], 0, 0, 0);
                acc[3][3] = __builtin_amdgcn_mfma_f32_16x16x32_bf16(af3, bf3, acc[3][3], 0, 0, 0);
            }
        }
        // epilogue: BN + SiLU + router weight
        const float we = wexp[(b << 2) + e];
#pragma unroll
        for (int mf = 0; mf < 4; ++mf) {
#pragma unroll
            for (int j = 0; j < 4; ++j) {
                const int co = mf * 16 + (kl << 2) + j;
                const float sc = scale[(e << 6) + co];
                const float sh = shift[(e << 6) + co];
#pragma unroll
                for (int nf = 0; nf < 4; ++nf) {
                    float y = acc[mf][nf][j] * sc + sh;
                    float s = y * __builtin_amdgcn_rcpf(1.f + __expf(-y));
                    oacc[mf][nf][j] += we * s;
                }
            }
        }
    }
    // store NCHW f32: per instr 4 co-rows x 16 consecutive w (64B segments)
#pragma unroll
    for (int mf = 0; mf < 4; ++mf) {
#pragma unroll
        for (int nf = 0; nf < 4; ++nf) {
            const int y = h0 + 2 * wv + (nf >> 1);
            const int x = w0 + (nf & 1) * 16 + l15;
#pragma unroll
            for (int j = 0; j < 4; ++j) {
                const int co = mf * 16 + (kl << 2) + j;
                out[(((long)(b * 64 + co)) * 160 + y) * 160 + x] = oacc[mf][nf][j];
            }
        }
    }
}

extern "C" void kernel_launch(void* const* d_in, const int* in_sizes, int n_in,
                              void* d_out, int out_size, void* d_ws, size_t ws_size,
                              hipStream_t stream) {
    const float* x = (const float*)d_in[0];
    const float* fc1w = (const float*)d_in[1];
    const float* fc2w = (const float*)d_in[2];
    const float* fc2b = (const float*)d_in[3];
    const float* convw = (const float*)d_in[4];
    const float* gamma = (const float*)d_in[5];
    const float* beta = (const float*)d_in[6];
    const float* mean = (const float*)d_in[7];
    const float* var = (const float*)d_in[8];
    float* out = (float*)d_out;
    char* ws = (char*)d_ws;
    u16* xt = (u16*)(ws + OFF_XT);
    u16* wtb = (u16*)(ws + OFF_WT);
    float* scale = (float*)(ws + OFF_SC);
    float* shift = (float*)(ws + OFF_SH);
    float* g = (float*)(ws + OFF_G);
    float* wexp = (float*)(ws + OFF_WE);
    float* gpart = (float*)(ws + OFF_GP);

    hipFuncSetAttribute((const void*)conv_main,
                        hipFuncAttributeMaxDynamicSharedMemorySize, SMEM_TOTAL);

    zero_border<<<16 * 162, 256, 0, stream>>>(xt);
    prep_w<<<576, 256, 0, stream>>>(convw, wtb, gamma, beta, mean, var, scale, shift);
    prep_x<<<12800, 256, 0, stream>>>(x, xt, gpart);
    g_reduce<<<1024, 256, 0, stream>>>(gpart, g);
    router<<<1, 256, 0, stream>>>(g, fc1w, fc2w, fc2b, wexp);
    conv_main<<<1600, 256, SMEM_TOTAL, stream>>>(xt, wtb, scale, shift, wexp, out);
}

// Round 7
// 177.068 us; speedup vs baseline: 1.0333x; 1.0333x over previous
//
#include <hip/hip_runtime.h>
#include <hip/hip_bf16.h>

typedef unsigned short u16;
typedef unsigned int   u32;
typedef __attribute__((ext_vector_type(8))) short s16x8;
typedef __attribute__((ext_vector_type(4))) float f32x4;

#define BN_EPS 1e-3f
// problem dims
#define NB 16
#define NC 64
#define NH 160
#define NW 160
#define NE 4
#define NR 16
#define HP 162   // padded H
#define WPD 162  // padded W

// workspace layout (bytes)
#define OFF_XT 0UL
#define SZ_XT  (16UL*162*162*64*2)     // 53,747,712  padded NHWC bf16
#define OFF_WT (OFF_XT + SZ_XT)
#define SZ_WT  (4UL*64*9*64*2)         // 294,912  [e][ch][tap][cio][co][8ci] bf16
#define OFF_SC (OFF_WT + SZ_WT)        // bn scale [4][64] f32
#define OFF_SH (OFF_SC + 1024UL)       // bn shift [4][64] f32
#define OFF_G  (OFF_SH + 1024UL)       // g [16][64] f32
#define OFF_WE (OFF_G + 4096UL)        // wexp [16][4] f32
#define OFF_GP (OFF_WE + 256UL)        // gpart [1024][800] f32 (3.28 MB)

// conv_main LDS partition (dynamic, 80,640 B total -> 2 blocks/CU)
// xls cg-stride padded to 342 px (5472 B): staging-write lane start-banks
// become {0,24,16,8,4,28,20,12}x2 = 2-way (free) instead of {0,16}x4.
#define XSTRIDE 342
#define XLS_BYTES (8 * XSTRIDE * 16)   // 43,776
#define WLS_BYTES (2304 * 16)          // 36,864 = 36 k-octets x 64 co x 16 B
#define SMEM_TOTAL (XLS_BYTES + WLS_BYTES)

__device__ __forceinline__ u16 f2bf(float f) {
    u32 u = __builtin_bit_cast(u32, f);
    u += 0x7fffu + ((u >> 16) & 1u);   // round-to-nearest-even
    return (u16)(u >> 16);
}

// ---- weights [E][Co][Ci][3][3] f32 -> [e][ch][tap][cio][co][8ci] bf16 ----
// (each (e,ch) half-ci panel = 36,864 B linear; DMA round r = tap r's panel)
__global__ void prep_w(const float* __restrict__ cw, u16* __restrict__ wt,
                       const float* __restrict__ gamma, const float* __restrict__ beta,
                       const float* __restrict__ mean, const float* __restrict__ var,
                       float* __restrict__ scale, float* __restrict__ shift) {
    int idx = blockIdx.x * 256 + threadIdx.x;
    if (idx < 4 * 2 * 9 * 4 * 64 * 8) {
        int cin = idx & 7;
        int t = idx >> 3;
        int co = t & 63; t >>= 6;
        int cio = t & 3; t >>= 2;
        int tap = t % 9; t /= 9;
        int ch = t & 1;
        int e = t >> 1;
        int ci = ch * 32 + cio * 8 + cin;
        wt[idx] = f2bf(cw[(((long)(e * 64 + co)) * 64 + ci) * 9 + tap]);
    }
    if (idx < 256) {
        float sc = gamma[idx] * rsqrtf(var[idx] + BN_EPS);
        scale[idx] = sc;
        shift[idx] = beta[idx] - mean[idx] * sc;
    }
}

// ---- x NCHW f32 -> padded NHWC bf16 + router partials + border zero ------
// grid 15,392 = 12,800 transpose blocks + 2,592 border blocks
__global__ void prep_x(const float* __restrict__ x, u16* __restrict__ xt,
                       float* __restrict__ gpart) {
    __shared__ float tile[64][33];
    int blk = blockIdx.x;
    int t = threadIdx.x;
    if (blk >= 12800) {                // zero the 1-px halo border
        int bb = blk - 12800;          // 0..2591 = b*162 + hp
        int hp = bb % 162, b = bb / 162;
        u32* row = (u32*)xt + (((long)b * 162 + hp) * 162) * 32;
        if (hp == 0 || hp == 161) {
            for (int i = t; i < 162 * 32; i += 256) row[i] = 0u;
        } else if (t < 64) {
            int p = (t >> 5) ? 161 : 0;
            row[p * 32 + (t & 31)] = 0u;
        }
        return;
    }
    int wt5 = blk % 5;
    int tmp = blk / 5;
    int h = tmp % 160, b = tmp / 160;
    int w0 = wt5 * 32;
    int w = t & 31, c0 = t >> 5;       // c0 in 0..7
#pragma unroll
    for (int i = 0; i < 8; ++i) {
        int c = c0 + 8 * i;
        tile[c][w] = x[(((long)b * 64 + c) * 160 + h) * 160 + w0 + w];
    }
    __syncthreads();
    if (t < 64) {                      // per-channel partial sum over 32 w
        float s = 0.f;
#pragma unroll
        for (int wi = 0; wi < 32; ++wi) s += tile[t][wi];
        gpart[((long)(b * 64 + t)) * 800 + h * 5 + wt5] = s;
    }
    // write NHWC bf16 (padded coords h+1, w+1), coalesced u32 (2 channels)
    u32* xt32 = (u32*)xt;
    long base = ((((long)b * 162 + h + 1) * 162) + (w0 + 1)) * 32; // u32 index
#pragma unroll
    for (int j = 0; j < 4; ++j) {
        int idx = t + 256 * j;         // 0..1023
        int p = idx >> 5, cp = idx & 31;
        float v0 = tile[2 * cp][p], v1 = tile[2 * cp + 1][p];
        xt32[base + p * 32 + cp] = (u32)f2bf(v0) | ((u32)f2bf(v1) << 16);
    }
}

// ---- finish global average pool ------------------------------------------
__global__ void g_reduce(const float* __restrict__ gpart, float* __restrict__ g) {
    int id = blockIdx.x;               // 1024 = b*64+c
    int t = threadIdx.x;
    float s = 0.f;
    for (int i = t; i < 800; i += 256) s += gpart[(long)id * 800 + i];
#pragma unroll
    for (int off = 32; off > 0; off >>= 1) s += __shfl_down(s, off, 64);
    __shared__ float red[4];
    if ((t & 63) == 0) red[t >> 6] = s;
    __syncthreads();
    if (t == 0) g[id] = (red[0] + red[1] + red[2] + red[3]) * (1.f / 25600.f);
}

// ---- router: fc1 -> relu -> fc2 -> softmax -------------------------------
__global__ void router(const float* __restrict__ g, const float* __restrict__ fc1w,
                       const float* __restrict__ fc2w, const float* __restrict__ fc2b,
                       float* __restrict__ wexp) {
    __shared__ float gL[16][64];
    __shared__ float h1[16][16];
    __shared__ float z[16][4];
    int t = threadIdx.x;
    for (int i = t; i < 1024; i += 256) gL[i >> 6][i & 63] = g[i];
    __syncthreads();
    {
        int b = t >> 4, r = t & 15;
        float s = 0.f;
#pragma unroll
        for (int c = 0; c < 64; ++c) s += gL[b][c] * fc1w[r * 64 + c];
        h1[b][r] = fmaxf(s, 0.f);
    }
    __syncthreads();
    if (t < 64) {
        int b = t >> 2, e = t & 3;
        float s = fc2b[e];
#pragma unroll
        for (int r = 0; r < 16; ++r) s += h1[b][r] * fc2w[e * 16 + r];
        z[b][e] = s;
    }
    __syncthreads();
    if (t < 16) {
        int b = t;
        float m = fmaxf(fmaxf(z[b][0], z[b][1]), fmaxf(z[b][2], z[b][3]));
        float e0 = __expf(z[b][0] - m), e1 = __expf(z[b][1] - m);
        float e2 = __expf(z[b][2] - m), e3 = __expf(z[b][3] - m);
        float inv = 1.f / (e0 + e1 + e2 + e3);
        wexp[b * 4 + 0] = e0 * inv; wexp[b * 4 + 1] = e1 * inv;
        wexp[b * 4 + 2] = e2 * inv; wexp[b * 4 + 3] = e3 * inv;
    }
}

// ---- main: 4-expert implicit-GEMM conv + BN + SiLU + weighted sum --------
// grid 1600 = 16 b * 20 htile * 5 wtile ; block 256 (4 waves)
// Wave tile M=64co x N=64px. x in LDS [cg][P@342] (conflict-free both on
// staging write and B-read); weight DMA round r == tap r -> counted-vmcnt
// 2-phase overlap: wait vmcnt(4) -> taps 0-4, wait vmcnt(0) -> taps 5-8.
__global__ __launch_bounds__(256, 2) void conv_main(
    const u16* __restrict__ xt, const u16* __restrict__ wt,
    const float* __restrict__ scale, const float* __restrict__ shift,
    const float* __restrict__ wexp, float* __restrict__ out) {
    extern __shared__ char smem[];
    u16* xls = (u16*)smem;                       // [cg 8][P 342] octets
    u16* wls = (u16*)(smem + XLS_BYTES);         // [t 36][co 64] octets

    // bijective chunked XCD swizzle (1600 % 8 == 0): XCD k gets 2 batches
    const int o = blockIdx.x;
    const int blk = (o & 7) * 200 + (o >> 3);
    const int wt5 = blk % 5;
    const int tmp = blk / 5;
    const int ht = tmp % 20;
    const int b = tmp / 20;
    const int h0 = ht * 8, w0 = wt5 * 32;
    const int tid = threadIdx.x;
    const int lane = tid & 63;
    const int wv = tid >> 6;
    const int l15 = lane & 15, kl = lane >> 4;

    // stage x halo tile (rows h0..h0+9, cols w0..w0+33) into [cg][P@342]
    {
        const u16* xb = xt + (long)b * HP * WPD * 64;
        for (int c = tid; c < 2720; c += 256) {
            int P = c >> 3, cg = c & 7;        // cg fast -> coalesced global
            int y = P / 34, px = P - y * 34;
            const u16* src = xb + (((long)(h0 + y) * WPD) + (w0 + px)) * 64 + cg * 8;
            s16x8 v = *(const s16x8*)src;
            *(s16x8*)(&xls[(cg * XSTRIDE + P) << 3]) = v;
        }
    }

    int Pbase[4];
#pragma unroll
    for (int nf = 0; nf < 4; ++nf)
        Pbase[nf] = (2 * wv + (nf >> 1)) * 34 + (nf & 1) * 16 + l15;

    // A base (u16 index into wls): octet (tap*4+kl)*64 + mf*16 + l15
    const int oA = (kl * 64 + l15) << 3;         // + tap*2048 + mf*128

    f32x4 oacc[4][4];
#pragma unroll
    for (int i = 0; i < 4; ++i)
#pragma unroll
        for (int j = 0; j < 4; ++j) oacc[i][j] = (f32x4)(0.f);

#pragma unroll 1
    for (int e = 0; e < 4; ++e) {
        f32x4 acc[4][4];
#pragma unroll
        for (int i = 0; i < 4; ++i)
#pragma unroll
            for (int j = 0; j < 4; ++j) acc[i][j] = (f32x4)(0.f);

#pragma unroll 1
        for (int ch = 0; ch < 2; ++ch) {
            // wls free only after all waves finished the previous round
            __syncthreads();
            // issue the 9 DMA rounds (round r == tap r's 256-octet panel)
            {
                const u16* wsrc = wt + ((long)(e * 2 + ch)) * 2304 * 8;
#pragma unroll
                for (int r = 0; r < 9; ++r) {
                    int oo = r * 256 + tid;      // octet index
                    __builtin_amdgcn_global_load_lds(
                        (const __attribute__((address_space(1))) void*)(wsrc + oo * 8),
                        (__attribute__((address_space(3))) void*)(wls + oo * 8),
                        16, 0, 0);
                }
            }
            // B bases for this ch (u16 index); tap adds only immediates
            int oB0 = (((ch * 4 + kl) * XSTRIDE) + Pbase[0]) << 3;
            int oB1 = (((ch * 4 + kl) * XSTRIDE) + Pbase[1]) << 3;
            int oB2 = (((ch * 4 + kl) * XSTRIDE) + Pbase[2]) << 3;
            int oB3 = (((ch * 4 + kl) * XSTRIDE) + Pbase[3]) << 3;

            auto tap_body = [&](int tap) {
                const int dy = tap / 3, dx = tap - 3 * dy;
                const int poff8 = (dy * 34 + dx) << 3;   // immediate
                const int at = oA + tap * 2048;          // immediate add
                s16x8 af0 = *(const s16x8*)(&wls[at]);
                s16x8 af1 = *(const s16x8*)(&wls[at + 128]);
                s16x8 af2 = *(const s16x8*)(&wls[at + 256]);
                s16x8 af3 = *(const s16x8*)(&wls[at + 384]);
                s16x8 bf0 = *(const s16x8*)(&xls[oB0 + poff8]);
                s16x8 bf1 = *(const s16x8*)(&xls[oB1 + poff8]);
                s16x8 bf2 = *(const s16x8*)(&xls[oB2 + poff8]);
                s16x8 bf3 = *(const s16x8*)(&xls[oB3 + poff8]);
                acc[0][0] = __builtin_amdgcn_mfma_f32_16x16x32_bf16(af0, bf0, acc[0][0], 0, 0, 0);
                acc[1][0] = __builtin_amdgcn_mfma_f32_16x16x32_bf16(af1, bf0, acc[1][0], 0, 0, 0);
                acc[2][0] = __builtin_amdgcn_mfma_f32_16x16x32_bf16(af2, bf0, acc[2][0], 0, 0, 0);
                acc[3][0] = __builtin_amdgcn_mfma_f32_16x16x32_bf16(af3, bf0, acc[3][0], 0, 0, 0);
                acc[0][1] = __builtin_amdgcn_mfma_f32_16x16x32_bf16(af0, bf1, acc[0][1], 0, 0, 0);
                acc[1][1] = __builtin_amdgcn_mfma_f32_16x16x32_bf16(af1, bf1, acc[1][1], 0, 0, 0);
                acc[2][1] = __builtin_amdgcn_mfma_f32_16x16x32_bf16(af2, bf1, acc[2][1], 0, 0, 0);
                acc[3][1] = __builtin_amdgcn_mfma_f32_16x16x32_bf16(af3, bf1, acc[3][1], 0, 0, 0);
                acc[0][2] = __builtin_amdgcn_mfma_f32_16x16x32_bf16(af0, bf2, acc[0][2], 0, 0, 0);
                acc[1][2] = __builtin_amdgcn_mfma_f32_16x16x32_bf16(af1, bf2, acc[1][2], 0, 0, 0);
                acc[2][2] = __builtin_amdgcn_mfma_f32_16x16x32_bf16(af2, bf2, acc[2][2], 0, 0, 0);
                acc[3][2] = __builtin_amdgcn_mfma_f32_16x16x32_bf16(af3, bf2, acc[3][2], 0, 0, 0);
                acc[0][3] = __builtin_amdgcn_mfma_f32_16x16x32_bf16(af0, bf3, acc[0][3], 0, 0, 0);
                acc[1][3] = __builtin_amdgcn_mfma_f32_16x16x32_bf16(af1, bf3, acc[1][3], 0, 0, 0);
                acc[2][3] = __builtin_amdgcn_mfma_f32_16x16x32_bf16(af2, bf3, acc[2][3], 0, 0, 0);
                acc[3][3] = __builtin_amdgcn_mfma_f32_16x16x32_bf16(af3, bf3, acc[3][3], 0, 0, 0);
            };

            // phase 1: taps 0-4 ready when this wave's vmcnt<=4 AND all
            // waves passed the same wait (barrier). lgkmcnt(0) makes the
            // xls ds_writes visible across waves on the first round.
            __builtin_amdgcn_s_waitcnt(0x074);   // vmcnt(4) lgkmcnt(0)
            __builtin_amdgcn_s_barrier();
            __builtin_amdgcn_sched_barrier(0);
#pragma unroll
            for (int tap = 0; tap < 5; ++tap) tap_body(tap);

            // phase 2: taps 5-8 after full DMA drain
            __builtin_amdgcn_s_waitcnt(0xF70);   // vmcnt(0)
            __builtin_amdgcn_s_barrier();
            __builtin_amdgcn_sched_barrier(0);
#pragma unroll
            for (int tap = 5; tap < 9; ++tap) tap_body(tap);
        }
        // epilogue: BN + SiLU + router weight
        const float we = wexp[(b << 2) + e];
#pragma unroll
        for (int mf = 0; mf < 4; ++mf) {
#pragma unroll
            for (int j = 0; j < 4; ++j) {
                const int co = mf * 16 + (kl << 2) + j;
                const float sc = scale[(e << 6) + co];
                const float sh = shift[(e << 6) + co];
#pragma unroll
                for (int nf = 0; nf < 4; ++nf) {
                    float y = acc[mf][nf][j] * sc + sh;
                    float s = y * __builtin_amdgcn_rcpf(1.f + __expf(-y));
                    oacc[mf][nf][j] += we * s;
                }
            }
        }
    }
    // store NCHW f32: per instr 4 co-rows x 16 consecutive w (64B segments)
#pragma unroll
    for (int mf = 0; mf < 4; ++mf) {
#pragma unroll
        for (int nf = 0; nf < 4; ++nf) {
            const int y = h0 + 2 * wv + (nf >> 1);
            const int x = w0 + (nf & 1) * 16 + l15;
#pragma unroll
            for (int j = 0; j < 4; ++j) {
                const int co = mf * 16 + (kl << 2) + j;
                out[(((long)(b * 64 + co)) * 160 + y) * 160 + x] = oacc[mf][nf][j];
            }
        }
    }
}

extern "C" void kernel_launch(void* const* d_in, const int* in_sizes, int n_in,
                              void* d_out, int out_size, void* d_ws, size_t ws_size,
                              hipStream_t stream) {
    const float* x = (const float*)d_in[0];
    const float* fc1w = (const float*)d_in[1];
    const float* fc2w = (const float*)d_in[2];
    const float* fc2b = (const float*)d_in[3];
    const float* convw = (const float*)d_in[4];
    const float* gamma = (const float*)d_in[5];
    const float* beta = (const float*)d_in[6];
    const float* mean = (const float*)d_in[7];
    const float* var = (const float*)d_in[8];
    float* out = (float*)d_out;
    char* ws = (char*)d_ws;
    u16* xt = (u16*)(ws + OFF_XT);
    u16* wtb = (u16*)(ws + OFF_WT);
    float* scale = (float*)(ws + OFF_SC);
    float* shift = (float*)(ws + OFF_SH);
    float* g = (float*)(ws + OFF_G);
    float* wexp = (float*)(ws + OFF_WE);
    float* gpart = (float*)(ws + OFF_GP);

    hipFuncSetAttribute((const void*)conv_main,
                        hipFuncAttributeMaxDynamicSharedMemorySize, SMEM_TOTAL);

    prep_w<<<576, 256, 0, stream>>>(convw, wtb, gamma, beta, mean, var, scale, shift);
    prep_x<<<15392, 256, 0, stream>>>(x, xt, gpart);
    g_reduce<<<1024, 256, 0, stream>>>(gpart, g);
    router<<<1, 256, 0, stream>>>(g, fc1w, fc2w, fc2b, wexp);
    conv_main<<<1600, 256, SMEM_TOTAL, stream>>>(xt, wtb, scale, shift, wexp, out);
}